// Round 9
// baseline (580.631 us; speedup 1.0000x reference)
//
#include <hip/hip_runtime.h>
#include <hip/hip_bf16.h>
#include <math.h>

// TMSA R15: CORRECTNESS FIX on R14's mm_mlp epilogue.
// R14 bug: copy-out used row = tid>>2 (64 of 128 rows) -> rows 64-127 of each
// HIDc tile kept stale aliased XOUTc data; absmax 0.0156->0.0559 (passed only
// because the residual stream dominates the output). Fix: row = tid>>1, 2
// threads/row, 4 contiguous uint4 chunks each (full 128x64 tile).
// Everything else byte-identical to R14 (all kernels now <40us - top-5 is the
// harness's 40us workspace-poison fills).
//
// ws (bytes), guard 110,100,480. Per chunk c:
//   Hb   bf16 [0,31457280)            (both chunks, written once)
//   QKVc bf16 [31457280,78643200)     (dead after attn-mut)
//   XOUTc bf16 [78643200,110100480)   (dead after mm<1>)
//   TMPc fp32 [31457280,62914560)     (over dead QKV)
//   H2c  bf16 [62914560,78643200)     (over dead QKV)
//   HIDc bf16 [78643200,110100480)    (over dead XOUTc)

typedef __attribute__((ext_vector_type(8))) short bf16x8;
typedef __attribute__((ext_vector_type(4))) float f32x4;

#define SCALE2 (0.22360679774997896f * 1.44269504088896340f)  // d^-0.5 * log2(e)
#define CHROWS 65536
#define QPLANE 7864320u   // 65536*120 elems per q/k/v plane (chunk)

union B8U { bf16x8 v; uint4 u4; uint2 u2[2]; unsigned u[4]; short s[8]; };

__device__ __forceinline__ short bf16b(float f) {
    __hip_bfloat16 h = __float2bfloat16(f);
    return *reinterpret_cast<short*>(&h);
}
__device__ __forceinline__ float bf2f(short s) {
    return __uint_as_float(((unsigned)(unsigned short)s) << 16);
}
__device__ __forceinline__ unsigned packbf(float a, float b) {
    return (unsigned)(unsigned short)bf16b(a) |
           ((unsigned)(unsigned short)bf16b(b) << 16);
}

// LDS frag-index swizzle (R11-verified: writes 2-way free, reads contiguous)
__device__ __forceinline__ int swz(int idx) { return idx ^ ((idx >> 4) & 7); }

// partitioned row r -> global row g
__device__ __forceinline__ int rev_row(int r) {
    int w = r >> 8, t = r & 255;
    int w8 = w & 7, h8 = (w >> 3) & 7, d2 = (w >> 6) & 1, n2 = w >> 7;
    int www = t & 7, hh = (t >> 3) & 7, dd = (t >> 6) & 1, nn = t >> 7;
    int n = n2 * 2 + nn, d = d2 * 2 + dd;
    int Hc = h8 * 8 + hh, Wc = w8 * 8 + www;
    return ((n * 4 + d) << 12) + (Hc << 6) + Wc;
}
// global row g -> partitioned row
__device__ __forceinline__ int part_row(int g) {
    int ww = g & 63, hh = (g >> 6) & 63, d = (g >> 12) & 3, n = g >> 14;
    int w = ((n >> 1) * 2 + (d >> 1)) * 64 + ((hh >> 3) << 3) + (ww >> 3);
    int t = (((n & 1) * 2 + (d & 1)) << 6) + ((hh & 7) << 3) + (ww & 7);
    return (w << 8) + t;
}
__device__ __forceinline__ float gelu_exact(float x) {
    return 0.5f * x * (1.0f + erff(x * 0.70710678118654752f));
}

// load B-frag from a 20-elem bf16 row (stride 20), k = quad*8..+7, zero-padded.
__device__ __forceinline__ bf16x8 load_frag20(const short* row, int quad) {
    B8U r;
    const uint2* p = (const uint2*)(row + quad * 8);
    r.u2[0] = p[0]; r.u2[1] = p[1];
    if (quad == 2) { r.u[2] = 0; r.u[3] = 0; }
    else if (quad == 3) { r.u[0] = r.u[1] = r.u[2] = r.u[3] = 0; }
    return r.v;
}

// ---- W staging: fp32 (N x K) rows [bn,bn+64) -> bf16 frags, swizzled ------
template <int K>
__device__ __forceinline__ void stageW_frag(uint4* Wf, const float* __restrict__ W,
                                            int bn, int N, int tid) {
    constexpr int CH   = (K == 120) ? 16 : 32;    // padded chunks per row
    constexpr int NKT  = CH / 4;
    constexpr int ITER = 64 * CH / 256;
#pragma unroll
    for (int i = 0; i < ITER; ++i) {
        int c = i * 256 + tid;
        int row = c / CH, q = c % CH;
        int wr = bn + row; if (wr > N - 1) wr = N - 1;
        uint4 d = make_uint4(0u, 0u, 0u, 0u);
        if (q * 8 < K) {
            f32x4 w0 = *(const f32x4*)(W + (size_t)wr * K + q * 8);
            f32x4 w1 = *(const f32x4*)(W + (size_t)wr * K + q * 8 + 4);
            d = make_uint4(packbf(w0.x, w0.y), packbf(w0.z, w0.w),
                           packbf(w1.x, w1.y), packbf(w1.z, w1.w));
        }
        Wf[swz(((row >> 4) * NKT + (q >> 2)) * 64 + (q & 3) * 16 + (row & 15))] = d;
    }
}

// -------- LayerNorm (C=120) fp32 -> bf16, 2 rows/wave, width-32 butterfly ---
template <bool REMAP>
__global__ __launch_bounds__(256) void ln_kernel(const float* __restrict__ in,
                                                 const float* __restrict__ w,
                                                 const float* __restrict__ b,
                                                 short* __restrict__ out) {
    const int tid = threadIdx.x;
    const int lane = tid & 63, wave = tid >> 6;
    const int half = lane >> 5, hl = lane & 31;
    const int row = blockIdx.x * 8 + wave * 2 + half;
    const float* xr = in + (size_t)row * 120;
    f32x4 v = (f32x4){0.f, 0.f, 0.f, 0.f};
    if (hl < 30) v = *(const f32x4*)(xr + hl * 4);
    float s = (v.x + v.y) + (v.z + v.w);
#pragma unroll
    for (int off = 16; off; off >>= 1) s += __shfl_xor(s, off, 32);
    float mean = s * (1.f / 120.f);
    float d0 = v.x - mean, d1 = v.y - mean, d2 = v.z - mean, d3 = v.w - mean;
    float q = (hl < 30) ? (d0 * d0 + d1 * d1) + (d2 * d2 + d3 * d3) : 0.f;
#pragma unroll
    for (int off = 16; off; off >>= 1) q += __shfl_xor(q, off, 32);
    float rstd = rsqrtf(q * (1.f / 120.f) + 1e-5f);
    int orow = REMAP ? part_row(row) : row;
    if (hl < 30) {
        f32x4 wv = *(const f32x4*)(w + hl * 4);
        f32x4 bv = *(const f32x4*)(b + hl * 4);
        unsigned u0 = packbf(d0 * rstd * wv.x + bv.x, d1 * rstd * wv.y + bv.y);
        unsigned u1 = packbf(d2 * rstd * wv.z + bv.z, d3 * rstd * wv.w + bv.w);
        *(uint2*)(out + (size_t)orow * 120 + hl * 4) = make_uint2(u0, u1);
    }
}

// --- MFMA GEMM, W-in-LDS / A-direct. MT m-tiles/wave, NJ n-tiles/wave -------
// 4 waves = (4/NJ n-groups) x (NJ==2 ? 2 : 4 m-groups). Block M = waves_m*MT*16.
// MODE: 0 QKV scatter (q pre-scaled by SCALE2) | 1 proj(+x res -> TMPc local)
//       4 fc2(+TMPc res -> d_out @rev_row)
template <int MODE, int K, int N, int MT, int NJ>
__global__ __launch_bounds__(256) void mm(const short* __restrict__ A,
                                          const float* __restrict__ W,
                                          const float* __restrict__ bias,
                                          void* __restrict__ outp,
                                          const float* __restrict__ aux,
                                          int m0) {
    constexpr int NKT = (K + 31) / 32;        // 4 (K=120) or 8 (K=240)
    constexpr int WN  = 4 / NJ;               // waves along n
    constexpr int WM  = 4 / WN;               // waves along m
    __shared__ uint4 Wf[4 * NKT * 64];        // 16KB or 32KB
    const int tid = threadIdx.x;
    const int lane = tid & 63, wave = tid >> 6;
    const int quad = lane >> 4, l16 = lane & 15;
    const int wm = wave / WN, wn = wave % WN;
    const int bm  = blockIdx.x * (WM * MT * 16) + wm * (MT * 16);
    const int bnb = blockIdx.y * 64;
    const int wtile = wn * NJ;

    stageW_frag<K>(Wf, W, bnb, N, tid);

    const short* Ar[MT];
#pragma unroll
    for (int i = 0; i < MT; ++i) Ar[i] = A + (size_t)(bm + i * 16 + l16) * K;

    f32x4 acc[MT][NJ];
#pragma unroll
    for (int i = 0; i < MT; ++i)
#pragma unroll
        for (int j = 0; j < NJ; ++j) acc[i][j] = (f32x4){0.f, 0.f, 0.f, 0.f};

    __syncthreads();
#pragma unroll
    for (int kt = 0; kt < NKT; ++kt) {
        int k = kt * 32 + quad * 8;
        int kc = (k + 8 <= K) ? k : 0;        // clamp; W frag is zero there
        B8U bw[NJ];
#pragma unroll
        for (int j = 0; j < NJ; ++j)
            bw[j].u4 = Wf[swz(((wtile + j) * NKT + kt) * 64 + lane)];
#pragma unroll
        for (int i = 0; i < MT; ++i) {
            bf16x8 a = *(const bf16x8*)(Ar[i] + kc);
#pragma unroll
            for (int j = 0; j < NJ; ++j)
                acc[i][j] = __builtin_amdgcn_mfma_f32_16x16x32_bf16(a, bw[j].v, acc[i][j], 0, 0, 0);
        }
    }

#pragma unroll
    for (int j = 0; j < NJ; ++j) {
        const int n = bnb + (wtile + j) * 16 + l16;
        if (n >= N) continue;
        const float bs = bias[n];
        int which = 0, head = 0, e = 0;
        if (MODE == 0) { which = n / 120; int hn = n % 120; head = hn / 20; e = hn % 20; }
#pragma unroll
        for (int i = 0; i < MT; ++i) {
#pragma unroll
            for (int r = 0; r < 4; ++r) {
                int m = bm + i * 16 + quad * 4 + r;
                float val = acc[i][j][r] + bs;
                if (MODE == 0) {
                    if (which == 0) val *= SCALE2;
                    int wl = m >> 8, t = m & 255;
                    ((short*)outp)[(size_t)which * QPLANE +
                                   ((size_t)((wl * 6 + head) * 256 + t)) * 20 + e] = bf16b(val);
                } else if (MODE == 1) {
                    int g = rev_row(m0 + m);
                    val += aux[(size_t)g * 120 + n];
                    ((float*)outp)[(size_t)m * 120 + n] = val;   // chunk-local
                } else { // MODE 4: aux = TMPc (chunk-local); scatter to d_out
                    int g = rev_row(m0 + m);
                    val += aux[(size_t)m * 120 + n];
                    ((float*)outp)[(size_t)g * 120 + n] = val;
                }
            }
        }
    }
}

// ---- fused MLP up-projection: HID = gelu(A@W1^T+b1) * (A@W2^T+b2) ----------
// MT=2/NJ=4: 8 A-loads feed 64 MFMAs/wave; acc 64 regs; W frags consumed
// one-at-a-time. Epilogue: LDS transpose (S[128][80] bf16 over dead Wf) ->
// coalesced uint4 copy-out (R15: FULL 128 rows - R14 covered only 64).
__global__ __launch_bounds__(256) void mm_mlp(const short* __restrict__ A,
                                              const float* __restrict__ W1,
                                              const float* __restrict__ b1,
                                              const float* __restrict__ W2,
                                              const float* __restrict__ b2,
                                              short* __restrict__ outp) {
    __shared__ uint4 Wf[2][1024];   // 32KB; epilogue aliases as S[128][80] bf16
    const int tid = threadIdx.x;
    const int lane = tid & 63, wave = tid >> 6;
    const int quad = lane >> 4, l16 = lane & 15;
    const int bm0 = blockIdx.x * 128;
    const int bnb = blockIdx.y * 64;
    const int N = 240;

    stageW_frag<120>(Wf[0], W1, bnb, N, tid);
    stageW_frag<120>(Wf[1], W2, bnb, N, tid);

    const short* Ar[2];
#pragma unroll
    for (int i = 0; i < 2; ++i)
        Ar[i] = A + (size_t)(bm0 + wave * 32 + i * 16 + l16) * 120;

    f32x4 acc1[2][4], acc2[2][4];
#pragma unroll
    for (int i = 0; i < 2; ++i)
#pragma unroll
        for (int j = 0; j < 4; ++j) {
            acc1[i][j] = (f32x4){0.f, 0.f, 0.f, 0.f};
            acc2[i][j] = (f32x4){0.f, 0.f, 0.f, 0.f};
        }

    __syncthreads();
#pragma unroll
    for (int kt = 0; kt < 4; ++kt) {
        int k = kt * 32 + quad * 8;
        int kc = (k + 8 <= 120) ? k : 0;
        bf16x8 a0 = *(const bf16x8*)(Ar[0] + kc);
        bf16x8 a1 = *(const bf16x8*)(Ar[1] + kc);
#pragma unroll
        for (int j = 0; j < 4; ++j) {
            B8U w1f; w1f.u4 = Wf[0][swz((j * 4 + kt) * 64 + lane)];
            acc1[0][j] = __builtin_amdgcn_mfma_f32_16x16x32_bf16(a0, w1f.v, acc1[0][j], 0, 0, 0);
            acc1[1][j] = __builtin_amdgcn_mfma_f32_16x16x32_bf16(a1, w1f.v, acc1[1][j], 0, 0, 0);
            B8U w2f; w2f.u4 = Wf[1][swz((j * 4 + kt) * 64 + lane)];
            acc2[0][j] = __builtin_amdgcn_mfma_f32_16x16x32_bf16(a0, w2f.v, acc2[0][j], 0, 0, 0);
            acc2[1][j] = __builtin_amdgcn_mfma_f32_16x16x32_bf16(a1, w2f.v, acc2[1][j], 0, 0, 0);
        }
    }

    // epilogue: gelu*v -> LDS tile (stride 80 shorts: quad-rows on disjoint
    // bank sets) -> coalesced uint4 copy-out
    __syncthreads();                     // all waves done reading Wf
    short* S = (short*)&Wf[0][0];        // [128][80]
#pragma unroll
    for (int j = 0; j < 4; ++j) {
        int n = bnb + j * 16 + l16;
        int ncl = n < N ? n : N - 1;
        float g1 = b1[ncl], g2 = b2[ncl];
#pragma unroll
        for (int i = 0; i < 2; ++i) {
#pragma unroll
            for (int r = 0; r < 4; ++r) {
                int lm = wave * 32 + i * 16 + quad * 4 + r;
                float gv = acc1[i][j][r] + g1;
                float vv = acc2[i][j][r] + g2;
                S[lm * 80 + j * 16 + l16] = bf16b(gelu_exact(gv) * vv);
            }
        }
    }
    __syncthreads();
    // R15 fix: 2 threads per row x 128 rows (was 4/row x 64 rows, leaving
    // rows 64-127 stale). Each thread writes 4 consecutive uint4 = 64B run.
    const int row2 = tid >> 1, sl = tid & 1;
#pragma unroll
    for (int s2 = 0; s2 < 4; ++s2) {
        int col = (sl * 4 + s2) * 8;
        if (bnb + col < N) {
            uint4 v = *(const uint4*)(S + row2 * 80 + col);
            *(uint4*)(outp + (size_t)(bm0 + row2) * 240 + bnb + col) = v;
        }
    }
}

// ---------------- MFMA flash attention, LDS-fed, zero-shuffle ----------------
template <int NK, bool MUT>
__global__ __launch_bounds__(NK) void attn_flash(const short* __restrict__ qkv,
                                                 short* __restrict__ xout) {
    constexpr int NKT = NK / 32;
    constexpr int VSTR2 = NK + 4;                  // u32 stride (16B-aligned rows)
    __shared__ __align__(16) short Kf[NKT * 2 * 48 * 8];
    __shared__ __align__(16) unsigned Vt2[11 * VSTR2];
    const int b = blockIdx.x;
    int wl, hd, half;
    if (MUT) { half = b & 1; hd = (b >> 1) % 6; wl = b / 12; }
    else     { half = 0;     hd = b % 6;        wl = b / 6;  }
    const int tid  = threadIdx.x;
    const int lane = tid & 63, wave = tid >> 6;
    const int quad = lane >> 4, l16 = lane & 15;

    const size_t rb = (size_t)(wl * 6 + hd) * 256;
    const short* qpl = qkv + rb * 20;
    const short* kpl = qkv + (size_t)QPLANE + rb * 20;
    const short* vpl = qkv + 2 * (size_t)QPLANE + rb * 20;
    const int koff = MUT ? half * 128 : 0;
    const int qoff = MUT ? (1 - half) * 128 : 0;

    // ---- stage V^T (u32 dim-pairs; row10 = ones at dim20) and K (frag order) ----
    {
        const uint2* p = (const uint2*)(vpl + (size_t)(koff + tid) * 20);
        unsigned tmp[10];
#pragma unroll
        for (int i = 0; i < 5; ++i) ((uint2*)tmp)[i] = p[i];
#pragma unroll
        for (int i = 0; i < 10; ++i) Vt2[i * VSTR2 + tid] = tmp[i];
        Vt2[10 * VSTR2 + tid] = 0x00003F80u;   // dim20 = bf16(1.0), dim21 = 0

        int skt = tid >> 5, sf = (tid >> 4) & 1, sl = tid & 15;
        int srow = koff + skt * 32 + sf * 4 + ((sl >> 2) << 3) + (sl & 3);
        const uint2* kp = (const uint2*)(kpl + (size_t)srow * 20);
        uint2 k0 = kp[0], k1 = kp[1], k2 = kp[2], k3 = kp[3], k4 = kp[4];
        uint4* dst = (uint4*)Kf + ((skt * 2 + sf) * 48 + sl);
        dst[0]  = make_uint4(k0.x, k0.y, k1.x, k1.y);   // quad0: d0-7
        dst[16] = make_uint4(k2.x, k2.y, k3.x, k3.y);   // quad1: d8-15
        dst[32] = make_uint4(k4.x, k4.y, 0u, 0u);       // quad2: d16-23
    }
    __syncthreads();

    const int quadc = quad < 3 ? quad : 2;             // quad3 aliases quad2 (x0)
    const uint4* kfrag = (const uint4*)Kf + quadc * 16 + l16;
    const unsigned sel = (l16 & 1) ? 0x07060302u : 0x05040100u;
    const unsigned* vbase0 = Vt2 + (l16 >> 1) * VSTR2;
    int r1 = 8 + (l16 >> 1); if (r1 > 10) r1 = 10;     // rows>=11 feed unused dims
    const unsigned* vbase1 = Vt2 + r1 * VSTR2;
    const f32x4 z4 = {0.f, 0.f, 0.f, 0.f};

#pragma unroll 1
    for (int g = 0; g < 2; ++g) {
        bf16x8 bq0 = load_frag20(qpl + (size_t)(qoff + wave * 64 + (g * 2 + 0) * 16 + l16) * 20, quad);
        bf16x8 bq1 = load_frag20(qpl + (size_t)(qoff + wave * 64 + (g * 2 + 1) * 16 + l16) * 20, quad);

        f32x4 accO[2][2];
        accO[0][0] = z4; accO[0][1] = z4; accO[1][0] = z4; accO[1][1] = z4;

#pragma unroll
        for (int kt = 0; kt < NKT; ++kt) {
            B8U ak0, ak1;
            ak0.u4 = kfrag[(kt * 2 + 0) * 48];
            ak1.u4 = kfrag[(kt * 2 + 1) * 48];
            B8U av0, av1;
            {
                uint4 va = *(const uint4*)(vbase0 + kt * 32 + quad * 8);
                uint4 vb = *(const uint4*)(vbase0 + kt * 32 + quad * 8 + 4);
                av0.u[0] = __builtin_amdgcn_perm(va.y, va.x, sel);
                av0.u[1] = __builtin_amdgcn_perm(va.w, va.z, sel);
                av0.u[2] = __builtin_amdgcn_perm(vb.y, vb.x, sel);
                av0.u[3] = __builtin_amdgcn_perm(vb.w, vb.z, sel);
                uint4 vc = *(const uint4*)(vbase1 + kt * 32 + quad * 8);
                uint4 vd = *(const uint4*)(vbase1 + kt * 32 + quad * 8 + 4);
                av1.u[0] = __builtin_amdgcn_perm(vc.y, vc.x, sel);
                av1.u[1] = __builtin_amdgcn_perm(vc.w, vc.z, sel);
                av1.u[2] = __builtin_amdgcn_perm(vd.y, vd.x, sel);
                av1.u[3] = __builtin_amdgcn_perm(vd.w, vd.z, sel);
            }
#pragma unroll
            for (int t = 0; t < 2; ++t) {
                bf16x8 bqt = t ? bq1 : bq0;
                f32x4 s0 = __builtin_amdgcn_mfma_f32_16x16x32_bf16(ak0.v, bqt, z4, 0, 0, 0);
                f32x4 s1 = __builtin_amdgcn_mfma_f32_16x16x32_bf16(ak1.v, bqt, z4, 0, 0, 0);
                float p0 = __builtin_amdgcn_exp2f(s0[0]), p1 = __builtin_amdgcn_exp2f(s0[1]);
                float p2 = __builtin_amdgcn_exp2f(s0[2]), p3 = __builtin_amdgcn_exp2f(s0[3]);
                float p4 = __builtin_amdgcn_exp2f(s1[0]), p5 = __builtin_amdgcn_exp2f(s1[1]);
                float p6 = __builtin_amdgcn_exp2f(s1[2]), p7 = __builtin_amdgcn_exp2f(s1[3]);
                B8U bp;   // P^T B-frag: j=0..3 <- s0 regs, j=4..7 <- s1 regs
                bp.u[0] = packbf(p0, p1);
                bp.u[1] = packbf(p2, p3);
                bp.u[2] = packbf(p4, p5);
                bp.u[3] = packbf(p6, p7);
                accO[t][0] = __builtin_amdgcn_mfma_f32_16x16x32_bf16(av0.v, bp.v, accO[t][0], 0, 0, 0);
                accO[t][1] = __builtin_amdgcn_mfma_f32_16x16x32_bf16(av1.v, bp.v, accO[t][1], 0, 0, 0);
            }
        }

        // epilogue: O^T C-layout (col l16=query, row quad*4+r=dim);
        // l = accO[t][1][0] on quad1 (dim20 ones-column)
#pragma unroll
        for (int t = 0; t < 2; ++t) {
            int nt = g * 2 + t;
            float l = __shfl(accO[t][1][0], 16 + l16, 64);
            float inv = 1.f / l;
            int tok = (MUT ? half * 128 : 0) + wave * 64 + nt * 16 + l16;
            short* orow = xout + (size_t)(wl * 256 + tok) * 240 + (MUT ? hd * 20 : 120 + hd * 20);
            unsigned lo = packbf(accO[t][0][0] * inv, accO[t][0][1] * inv);
            unsigned hi2 = packbf(accO[t][0][2] * inv, accO[t][0][3] * inv);
            *(uint2*)(orow + quad * 4) = make_uint2(lo, hi2);
            if (quad == 0) {
                unsigned lo2 = packbf(accO[t][1][0] * inv, accO[t][1][1] * inv);
                unsigned hi3 = packbf(accO[t][1][2] * inv, accO[t][1][3] * inv);
                *(uint2*)(orow + 16) = make_uint2(lo2, hi3);
            }
        }
    }
}

extern "C" void kernel_launch(void* const* d_in, const int* in_sizes, int n_in,
                              void* d_out, int out_size, void* d_ws, size_t ws_size,
                              hipStream_t stream) {
    const float* x          = (const float*)d_in[0];
    const float* norm1_w    = (const float*)d_in[1];
    const float* norm1_b    = (const float*)d_in[2];
    const float* qkv_self_w = (const float*)d_in[3];
    const float* qkv_self_b = (const float*)d_in[4];
    const float* qkv_mut_w  = (const float*)d_in[5];
    const float* qkv_mut_b  = (const float*)d_in[6];
    const float* proj_w     = (const float*)d_in[7];
    const float* proj_b     = (const float*)d_in[8];
    const float* norm2_w    = (const float*)d_in[9];
    const float* norm2_b    = (const float*)d_in[10];
    const float* fc11_w     = (const float*)d_in[11];
    const float* fc11_b     = (const float*)d_in[12];
    const float* fc12_w     = (const float*)d_in[13];
    const float* fc12_b     = (const float*)d_in[14];
    const float* fc2_w      = (const float*)d_in[15];
    const float* fc2_b      = (const float*)d_in[16];

    if (ws_size < 110100480u) return;

    char* wsb   = (char*)d_ws;
    short* Hb    = (short*)wsb;                   // 131072x120 bf16
    short* QKVc  = (short*)(wsb + 31457280);      // 3 planes, chunk
    short* XOUTc = (short*)(wsb + 78643200);      // 65536x240 bf16
    float* TMPc  = (float*)(wsb + 31457280);      // 65536x120 fp32 (over dead QKV)
    short* H2c   = (short*)(wsb + 62914560);      // 65536x120 bf16 (over dead QKV)
    short* HIDc  = (short*)(wsb + 78643200);      // 65536x240 bf16 (over dead XOUT)
    float* out   = (float*)d_out;                 // final output only

    // 1. LN1 + window partition -> Hb (bf16)
    ln_kernel<true><<<16384, 256, 0, stream>>>(x, norm1_w, norm1_b, Hb);

    // 2. Per-chunk: attention + MLP (row-local after attn; no d_out scratch)
    for (int c = 0; c < 2; ++c) {
        int m0 = c * CHROWS;
        const short* Ac = Hb + (size_t)m0 * 120;
        mm<0, 120, 360, 4, 4><<<dim3(256, 6), 256, 0, stream>>>(Ac, qkv_self_w, qkv_self_b,
                                                                QKVc, nullptr, 0);
        attn_flash<256, false><<<1536, 256, 0, stream>>>(QKVc, XOUTc);
        mm<0, 120, 360, 4, 4><<<dim3(256, 6), 256, 0, stream>>>(Ac, qkv_mut_w, qkv_mut_b,
                                                                QKVc, nullptr, 0);
        attn_flash<128, true><<<3072, 128, 0, stream>>>(QKVc, XOUTc);
        mm<1, 240, 120, 4, 4><<<dim3(256, 2), 256, 0, stream>>>(XOUTc, proj_w, proj_b,
                                                                TMPc, x, m0);
        ln_kernel<false><<<8192, 256, 0, stream>>>(TMPc, norm2_w, norm2_b, H2c);
        mm_mlp<<<dim3(512, 4), 256, 0, stream>>>(H2c, fc11_w, fc11_b,
                                                 fc12_w, fc12_b, HIDc);
        mm<4, 240, 120, 4, 4><<<dim3(256, 2), 256, 0, stream>>>(HIDc, fc2_w, fc2_b,
                                                                out, TMPc, m0);
    }
}

// Round 10
// 563.170 us; speedup vs baseline: 1.0310x; 1.0310x over previous
//
#include <hip/hip_runtime.h>
#include <hip/hip_bf16.h>
#include <math.h>

// TMSA R16: mm_mlp VALU + staging diet.
// R15 post-mortem: LDS-transpose epilogue (46us) LOSES to plain scatter (R13:
// 43us) once correct; mm_mlp's real costs are erff (~1200 of ~1850 VALU
// instr/wave) and per-128-row W re-staging. R16 (mm_mlp only, clean A/B):
//  - fast erf (A&S 7.1.26 + v_exp_f32, |err|<=1.5e-7): ~12 ops vs ~35-40.
//  - 512-thread/8-wave block, M=256: W staged once per 256 rows (staging /2).
//  - scatter epilogue restored.
// Everything else byte-identical to R15.
//
// ws (bytes), guard 110,100,480. Per chunk c:
//   Hb   bf16 [0,31457280)            (both chunks, written once)
//   QKVc bf16 [31457280,78643200)     (dead after attn-mut)
//   XOUTc bf16 [78643200,110100480)   (dead after mm<1>)
//   TMPc fp32 [31457280,62914560)     (over dead QKV)
//   H2c  bf16 [62914560,78643200)     (over dead QKV)
//   HIDc bf16 [78643200,110100480)    (over dead XOUTc)

typedef __attribute__((ext_vector_type(8))) short bf16x8;
typedef __attribute__((ext_vector_type(4))) float f32x4;

#define SCALE2 (0.22360679774997896f * 1.44269504088896340f)  // d^-0.5 * log2(e)
#define CHROWS 65536
#define QPLANE 7864320u   // 65536*120 elems per q/k/v plane (chunk)

union B8U { bf16x8 v; uint4 u4; uint2 u2[2]; unsigned u[4]; short s[8]; };

__device__ __forceinline__ short bf16b(float f) {
    __hip_bfloat16 h = __float2bfloat16(f);
    return *reinterpret_cast<short*>(&h);
}
__device__ __forceinline__ float bf2f(short s) {
    return __uint_as_float(((unsigned)(unsigned short)s) << 16);
}
__device__ __forceinline__ unsigned packbf(float a, float b) {
    return (unsigned)(unsigned short)bf16b(a) |
           ((unsigned)(unsigned short)bf16b(b) << 16);
}

// LDS frag-index swizzle (R11-verified: writes 2-way free, reads contiguous)
__device__ __forceinline__ int swz(int idx) { return idx ^ ((idx >> 4) & 7); }

// partitioned row r -> global row g
__device__ __forceinline__ int rev_row(int r) {
    int w = r >> 8, t = r & 255;
    int w8 = w & 7, h8 = (w >> 3) & 7, d2 = (w >> 6) & 1, n2 = w >> 7;
    int www = t & 7, hh = (t >> 3) & 7, dd = (t >> 6) & 1, nn = t >> 7;
    int n = n2 * 2 + nn, d = d2 * 2 + dd;
    int Hc = h8 * 8 + hh, Wc = w8 * 8 + www;
    return ((n * 4 + d) << 12) + (Hc << 6) + Wc;
}
// global row g -> partitioned row
__device__ __forceinline__ int part_row(int g) {
    int ww = g & 63, hh = (g >> 6) & 63, d = (g >> 12) & 3, n = g >> 14;
    int w = ((n >> 1) * 2 + (d >> 1)) * 64 + ((hh >> 3) << 3) + (ww >> 3);
    int t = (((n & 1) * 2 + (d & 1)) << 6) + ((hh & 7) << 3) + (ww & 7);
    return (w << 8) + t;
}
__device__ __forceinline__ float gelu_exact(float x) {
    return 0.5f * x * (1.0f + erff(x * 0.70710678118654752f));
}
// gelu via A&S 7.1.26 erf approx (|err|<=1.5e-7) + hardware exp
__device__ __forceinline__ float gelu_fast(float x) {
    float z = x * 0.70710678118654752f;
    float az = fabsf(z);
    float t = 1.0f / fmaf(0.3275911f, az, 1.0f);
    float poly = t * fmaf(t, fmaf(t, fmaf(t, fmaf(t, 1.061405429f, -1.453152027f),
                                          1.421413741f), -0.284496736f), 0.254829592f);
    float e = __expf(-az * az);
    float erfv = 1.0f - poly * e;
    erfv = copysignf(erfv, z);
    return 0.5f * x * (1.0f + erfv);
}

// load B-frag from a 20-elem bf16 row (stride 20), k = quad*8..+7, zero-padded.
__device__ __forceinline__ bf16x8 load_frag20(const short* row, int quad) {
    B8U r;
    const uint2* p = (const uint2*)(row + quad * 8);
    r.u2[0] = p[0]; r.u2[1] = p[1];
    if (quad == 2) { r.u[2] = 0; r.u[3] = 0; }
    else if (quad == 3) { r.u[0] = r.u[1] = r.u[2] = r.u[3] = 0; }
    return r.v;
}

// ---- W staging: fp32 (N x K) rows [bn,bn+64) -> bf16 frags, swizzled ------
template <int K, int TPB>
__device__ __forceinline__ void stageW_frag(uint4* Wf, const float* __restrict__ W,
                                            int bn, int N, int tid) {
    constexpr int CH   = (K == 120) ? 16 : 32;    // padded chunks per row
    constexpr int NKT  = CH / 4;
    constexpr int ITER = 64 * CH / TPB;
#pragma unroll
    for (int i = 0; i < ITER; ++i) {
        int c = i * TPB + tid;
        int row = c / CH, q = c % CH;
        int wr = bn + row; if (wr > N - 1) wr = N - 1;
        uint4 d = make_uint4(0u, 0u, 0u, 0u);
        if (q * 8 < K) {
            f32x4 w0 = *(const f32x4*)(W + (size_t)wr * K + q * 8);
            f32x4 w1 = *(const f32x4*)(W + (size_t)wr * K + q * 8 + 4);
            d = make_uint4(packbf(w0.x, w0.y), packbf(w0.z, w0.w),
                           packbf(w1.x, w1.y), packbf(w1.z, w1.w));
        }
        Wf[swz(((row >> 4) * NKT + (q >> 2)) * 64 + (q & 3) * 16 + (row & 15))] = d;
    }
}

// -------- LayerNorm (C=120) fp32 -> bf16, 2 rows/wave, width-32 butterfly ---
template <bool REMAP>
__global__ __launch_bounds__(256) void ln_kernel(const float* __restrict__ in,
                                                 const float* __restrict__ w,
                                                 const float* __restrict__ b,
                                                 short* __restrict__ out) {
    const int tid = threadIdx.x;
    const int lane = tid & 63, wave = tid >> 6;
    const int half = lane >> 5, hl = lane & 31;
    const int row = blockIdx.x * 8 + wave * 2 + half;
    const float* xr = in + (size_t)row * 120;
    f32x4 v = (f32x4){0.f, 0.f, 0.f, 0.f};
    if (hl < 30) v = *(const f32x4*)(xr + hl * 4);
    float s = (v.x + v.y) + (v.z + v.w);
#pragma unroll
    for (int off = 16; off; off >>= 1) s += __shfl_xor(s, off, 32);
    float mean = s * (1.f / 120.f);
    float d0 = v.x - mean, d1 = v.y - mean, d2 = v.z - mean, d3 = v.w - mean;
    float q = (hl < 30) ? (d0 * d0 + d1 * d1) + (d2 * d2 + d3 * d3) : 0.f;
#pragma unroll
    for (int off = 16; off; off >>= 1) q += __shfl_xor(q, off, 32);
    float rstd = rsqrtf(q * (1.f / 120.f) + 1e-5f);
    int orow = REMAP ? part_row(row) : row;
    if (hl < 30) {
        f32x4 wv = *(const f32x4*)(w + hl * 4);
        f32x4 bv = *(const f32x4*)(b + hl * 4);
        unsigned u0 = packbf(d0 * rstd * wv.x + bv.x, d1 * rstd * wv.y + bv.y);
        unsigned u1 = packbf(d2 * rstd * wv.z + bv.z, d3 * rstd * wv.w + bv.w);
        *(uint2*)(out + (size_t)orow * 120 + hl * 4) = make_uint2(u0, u1);
    }
}

// --- MFMA GEMM, W-in-LDS / A-direct. MT m-tiles/wave, NJ n-tiles/wave -------
// 4 waves = (4/NJ n-groups) x (NJ==2 ? 2 : 4 m-groups). Block M = waves_m*MT*16.
// MODE: 0 QKV scatter (q pre-scaled by SCALE2) | 1 proj(+x res -> TMPc local)
//       4 fc2(+TMPc res -> d_out @rev_row)
template <int MODE, int K, int N, int MT, int NJ>
__global__ __launch_bounds__(256) void mm(const short* __restrict__ A,
                                          const float* __restrict__ W,
                                          const float* __restrict__ bias,
                                          void* __restrict__ outp,
                                          const float* __restrict__ aux,
                                          int m0) {
    constexpr int NKT = (K + 31) / 32;        // 4 (K=120) or 8 (K=240)
    constexpr int WN  = 4 / NJ;               // waves along n
    constexpr int WM  = 4 / WN;               // waves along m
    __shared__ uint4 Wf[4 * NKT * 64];        // 16KB or 32KB
    const int tid = threadIdx.x;
    const int lane = tid & 63, wave = tid >> 6;
    const int quad = lane >> 4, l16 = lane & 15;
    const int wm = wave / WN, wn = wave % WN;
    const int bm  = blockIdx.x * (WM * MT * 16) + wm * (MT * 16);
    const int bnb = blockIdx.y * 64;
    const int wtile = wn * NJ;

    stageW_frag<K, 256>(Wf, W, bnb, N, tid);

    const short* Ar[MT];
#pragma unroll
    for (int i = 0; i < MT; ++i) Ar[i] = A + (size_t)(bm + i * 16 + l16) * K;

    f32x4 acc[MT][NJ];
#pragma unroll
    for (int i = 0; i < MT; ++i)
#pragma unroll
        for (int j = 0; j < NJ; ++j) acc[i][j] = (f32x4){0.f, 0.f, 0.f, 0.f};

    __syncthreads();
#pragma unroll
    for (int kt = 0; kt < NKT; ++kt) {
        int k = kt * 32 + quad * 8;
        int kc = (k + 8 <= K) ? k : 0;        // clamp; W frag is zero there
        B8U bw[NJ];
#pragma unroll
        for (int j = 0; j < NJ; ++j)
            bw[j].u4 = Wf[swz(((wtile + j) * NKT + kt) * 64 + lane)];
#pragma unroll
        for (int i = 0; i < MT; ++i) {
            bf16x8 a = *(const bf16x8*)(Ar[i] + kc);
#pragma unroll
            for (int j = 0; j < NJ; ++j)
                acc[i][j] = __builtin_amdgcn_mfma_f32_16x16x32_bf16(a, bw[j].v, acc[i][j], 0, 0, 0);
        }
    }

#pragma unroll
    for (int j = 0; j < NJ; ++j) {
        const int n = bnb + (wtile + j) * 16 + l16;
        if (n >= N) continue;
        const float bs = bias[n];
        int which = 0, head = 0, e = 0;
        if (MODE == 0) { which = n / 120; int hn = n % 120; head = hn / 20; e = hn % 20; }
#pragma unroll
        for (int i = 0; i < MT; ++i) {
#pragma unroll
            for (int r = 0; r < 4; ++r) {
                int m = bm + i * 16 + quad * 4 + r;
                float val = acc[i][j][r] + bs;
                if (MODE == 0) {
                    if (which == 0) val *= SCALE2;
                    int wl = m >> 8, t = m & 255;
                    ((short*)outp)[(size_t)which * QPLANE +
                                   ((size_t)((wl * 6 + head) * 256 + t)) * 20 + e] = bf16b(val);
                } else if (MODE == 1) {
                    int g = rev_row(m0 + m);
                    val += aux[(size_t)g * 120 + n];
                    ((float*)outp)[(size_t)m * 120 + n] = val;   // chunk-local
                } else { // MODE 4: aux = TMPc (chunk-local); scatter to d_out
                    int g = rev_row(m0 + m);
                    val += aux[(size_t)m * 120 + n];
                    ((float*)outp)[(size_t)g * 120 + n] = val;
                }
            }
        }
    }
}

// ---- fused MLP up-projection: HID = gelu(A@W1^T+b1) * (A@W2^T+b2) ----------
// R16: 512 threads / 8 waves, M=256 (W staged once per 256 rows). Per wave:
// MT=2 rows-tiles x NJ=4 n-tiles, each A-load feeds 8 MFMAs. Scatter epilogue
// with gelu_fast (A&S erf: ~12 VALU ops vs erff's ~35-40).
__global__ __launch_bounds__(512) void mm_mlp(const short* __restrict__ A,
                                              const float* __restrict__ W1,
                                              const float* __restrict__ b1,
                                              const float* __restrict__ W2,
                                              const float* __restrict__ b2,
                                              short* __restrict__ outp) {
    __shared__ uint4 Wf[2][1024];   // 32KB
    const int tid = threadIdx.x;
    const int lane = tid & 63, wave = tid >> 6;      // 0..7
    const int quad = lane >> 4, l16 = lane & 15;
    const int bm0 = blockIdx.x * 256;
    const int bnb = blockIdx.y * 64;
    const int N = 240;

    stageW_frag<120, 512>(Wf[0], W1, bnb, N, tid);
    stageW_frag<120, 512>(Wf[1], W2, bnb, N, tid);

    const short* Ar[2];
#pragma unroll
    for (int i = 0; i < 2; ++i)
        Ar[i] = A + (size_t)(bm0 + wave * 32 + i * 16 + l16) * 120;

    f32x4 acc1[2][4], acc2[2][4];
#pragma unroll
    for (int i = 0; i < 2; ++i)
#pragma unroll
        for (int j = 0; j < 4; ++j) {
            acc1[i][j] = (f32x4){0.f, 0.f, 0.f, 0.f};
            acc2[i][j] = (f32x4){0.f, 0.f, 0.f, 0.f};
        }

    __syncthreads();
#pragma unroll
    for (int kt = 0; kt < 4; ++kt) {
        int k = kt * 32 + quad * 8;
        int kc = (k + 8 <= 120) ? k : 0;
        bf16x8 a0 = *(const bf16x8*)(Ar[0] + kc);
        bf16x8 a1 = *(const bf16x8*)(Ar[1] + kc);
#pragma unroll
        for (int j = 0; j < 4; ++j) {
            B8U w1f; w1f.u4 = Wf[0][swz((j * 4 + kt) * 64 + lane)];
            acc1[0][j] = __builtin_amdgcn_mfma_f32_16x16x32_bf16(a0, w1f.v, acc1[0][j], 0, 0, 0);
            acc1[1][j] = __builtin_amdgcn_mfma_f32_16x16x32_bf16(a1, w1f.v, acc1[1][j], 0, 0, 0);
            B8U w2f; w2f.u4 = Wf[1][swz((j * 4 + kt) * 64 + lane)];
            acc2[0][j] = __builtin_amdgcn_mfma_f32_16x16x32_bf16(a0, w2f.v, acc2[0][j], 0, 0, 0);
            acc2[1][j] = __builtin_amdgcn_mfma_f32_16x16x32_bf16(a1, w2f.v, acc2[1][j], 0, 0, 0);
        }
    }

#pragma unroll
    for (int j = 0; j < 4; ++j) {
        const int n = bnb + j * 16 + l16;
        if (n >= N) continue;
        const float g1 = b1[n], g2 = b2[n];
#pragma unroll
        for (int i = 0; i < 2; ++i) {
#pragma unroll
            for (int r = 0; r < 4; ++r) {
                int m = bm0 + wave * 32 + i * 16 + quad * 4 + r;
                float gv = acc1[i][j][r] + g1;
                float vv = acc2[i][j][r] + g2;
                outp[(size_t)m * 240 + n] = bf16b(gelu_fast(gv) * vv);
            }
        }
    }
}

// ---------------- MFMA flash attention, LDS-fed, zero-shuffle ----------------
template <int NK, bool MUT>
__global__ __launch_bounds__(NK) void attn_flash(const short* __restrict__ qkv,
                                                 short* __restrict__ xout) {
    constexpr int NKT = NK / 32;
    constexpr int VSTR2 = NK + 4;                  // u32 stride (16B-aligned rows)
    __shared__ __align__(16) short Kf[NKT * 2 * 48 * 8];
    __shared__ __align__(16) unsigned Vt2[11 * VSTR2];
    const int b = blockIdx.x;
    int wl, hd, half;
    if (MUT) { half = b & 1; hd = (b >> 1) % 6; wl = b / 12; }
    else     { half = 0;     hd = b % 6;        wl = b / 6;  }
    const int tid  = threadIdx.x;
    const int lane = tid & 63, wave = tid >> 6;
    const int quad = lane >> 4, l16 = lane & 15;

    const size_t rb = (size_t)(wl * 6 + hd) * 256;
    const short* qpl = qkv + rb * 20;
    const short* kpl = qkv + (size_t)QPLANE + rb * 20;
    const short* vpl = qkv + 2 * (size_t)QPLANE + rb * 20;
    const int koff = MUT ? half * 128 : 0;
    const int qoff = MUT ? (1 - half) * 128 : 0;

    // ---- stage V^T (u32 dim-pairs; row10 = ones at dim20) and K (frag order) ----
    {
        const uint2* p = (const uint2*)(vpl + (size_t)(koff + tid) * 20);
        unsigned tmp[10];
#pragma unroll
        for (int i = 0; i < 5; ++i) ((uint2*)tmp)[i] = p[i];
#pragma unroll
        for (int i = 0; i < 10; ++i) Vt2[i * VSTR2 + tid] = tmp[i];
        Vt2[10 * VSTR2 + tid] = 0x00003F80u;   // dim20 = bf16(1.0), dim21 = 0

        int skt = tid >> 5, sf = (tid >> 4) & 1, sl = tid & 15;
        int srow = koff + skt * 32 + sf * 4 + ((sl >> 2) << 3) + (sl & 3);
        const uint2* kp = (const uint2*)(kpl + (size_t)srow * 20);
        uint2 k0 = kp[0], k1 = kp[1], k2 = kp[2], k3 = kp[3], k4 = kp[4];
        uint4* dst = (uint4*)Kf + ((skt * 2 + sf) * 48 + sl);
        dst[0]  = make_uint4(k0.x, k0.y, k1.x, k1.y);   // quad0: d0-7
        dst[16] = make_uint4(k2.x, k2.y, k3.x, k3.y);   // quad1: d8-15
        dst[32] = make_uint4(k4.x, k4.y, 0u, 0u);       // quad2: d16-23
    }
    __syncthreads();

    const int quadc = quad < 3 ? quad : 2;             // quad3 aliases quad2 (x0)
    const uint4* kfrag = (const uint4*)Kf + quadc * 16 + l16;
    const unsigned sel = (l16 & 1) ? 0x07060302u : 0x05040100u;
    const unsigned* vbase0 = Vt2 + (l16 >> 1) * VSTR2;
    int r1 = 8 + (l16 >> 1); if (r1 > 10) r1 = 10;     // rows>=11 feed unused dims
    const unsigned* vbase1 = Vt2 + r1 * VSTR2;
    const f32x4 z4 = {0.f, 0.f, 0.f, 0.f};

#pragma unroll 1
    for (int g = 0; g < 2; ++g) {
        bf16x8 bq0 = load_frag20(qpl + (size_t)(qoff + wave * 64 + (g * 2 + 0) * 16 + l16) * 20, quad);
        bf16x8 bq1 = load_frag20(qpl + (size_t)(qoff + wave * 64 + (g * 2 + 1) * 16 + l16) * 20, quad);

        f32x4 accO[2][2];
        accO[0][0] = z4; accO[0][1] = z4; accO[1][0] = z4; accO[1][1] = z4;

#pragma unroll
        for (int kt = 0; kt < NKT; ++kt) {
            B8U ak0, ak1;
            ak0.u4 = kfrag[(kt * 2 + 0) * 48];
            ak1.u4 = kfrag[(kt * 2 + 1) * 48];
            B8U av0, av1;
            {
                uint4 va = *(const uint4*)(vbase0 + kt * 32 + quad * 8);
                uint4 vb = *(const uint4*)(vbase0 + kt * 32 + quad * 8 + 4);
                av0.u[0] = __builtin_amdgcn_perm(va.y, va.x, sel);
                av0.u[1] = __builtin_amdgcn_perm(va.w, va.z, sel);
                av0.u[2] = __builtin_amdgcn_perm(vb.y, vb.x, sel);
                av0.u[3] = __builtin_amdgcn_perm(vb.w, vb.z, sel);
                uint4 vc = *(const uint4*)(vbase1 + kt * 32 + quad * 8);
                uint4 vd = *(const uint4*)(vbase1 + kt * 32 + quad * 8 + 4);
                av1.u[0] = __builtin_amdgcn_perm(vc.y, vc.x, sel);
                av1.u[1] = __builtin_amdgcn_perm(vc.w, vc.z, sel);
                av1.u[2] = __builtin_amdgcn_perm(vd.y, vd.x, sel);
                av1.u[3] = __builtin_amdgcn_perm(vd.w, vd.z, sel);
            }
#pragma unroll
            for (int t = 0; t < 2; ++t) {
                bf16x8 bqt = t ? bq1 : bq0;
                f32x4 s0 = __builtin_amdgcn_mfma_f32_16x16x32_bf16(ak0.v, bqt, z4, 0, 0, 0);
                f32x4 s1 = __builtin_amdgcn_mfma_f32_16x16x32_bf16(ak1.v, bqt, z4, 0, 0, 0);
                float p0 = __builtin_amdgcn_exp2f(s0[0]), p1 = __builtin_amdgcn_exp2f(s0[1]);
                float p2 = __builtin_amdgcn_exp2f(s0[2]), p3 = __builtin_amdgcn_exp2f(s0[3]);
                float p4 = __builtin_amdgcn_exp2f(s1[0]), p5 = __builtin_amdgcn_exp2f(s1[1]);
                float p6 = __builtin_amdgcn_exp2f(s1[2]), p7 = __builtin_amdgcn_exp2f(s1[3]);
                B8U bp;   // P^T B-frag: j=0..3 <- s0 regs, j=4..7 <- s1 regs
                bp.u[0] = packbf(p0, p1);
                bp.u[1] = packbf(p2, p3);
                bp.u[2] = packbf(p4, p5);
                bp.u[3] = packbf(p6, p7);
                accO[t][0] = __builtin_amdgcn_mfma_f32_16x16x32_bf16(av0.v, bp.v, accO[t][0], 0, 0, 0);
                accO[t][1] = __builtin_amdgcn_mfma_f32_16x16x32_bf16(av1.v, bp.v, accO[t][1], 0, 0, 0);
            }
        }

        // epilogue: O^T C-layout (col l16=query, row quad*4+r=dim);
        // l = accO[t][1][0] on quad1 (dim20 ones-column)
#pragma unroll
        for (int t = 0; t < 2; ++t) {
            int nt = g * 2 + t;
            float l = __shfl(accO[t][1][0], 16 + l16, 64);
            float inv = 1.f / l;
            int tok = (MUT ? half * 128 : 0) + wave * 64 + nt * 16 + l16;
            short* orow = xout + (size_t)(wl * 256 + tok) * 240 + (MUT ? hd * 20 : 120 + hd * 20);
            unsigned lo = packbf(accO[t][0][0] * inv, accO[t][0][1] * inv);
            unsigned hi2 = packbf(accO[t][0][2] * inv, accO[t][0][3] * inv);
            *(uint2*)(orow + quad * 4) = make_uint2(lo, hi2);
            if (quad == 0) {
                unsigned lo2 = packbf(accO[t][1][0] * inv, accO[t][1][1] * inv);
                unsigned hi3 = packbf(accO[t][1][2] * inv, accO[t][1][3] * inv);
                *(uint2*)(orow + 16) = make_uint2(lo2, hi3);
            }
        }
    }
}

extern "C" void kernel_launch(void* const* d_in, const int* in_sizes, int n_in,
                              void* d_out, int out_size, void* d_ws, size_t ws_size,
                              hipStream_t stream) {
    const float* x          = (const float*)d_in[0];
    const float* norm1_w    = (const float*)d_in[1];
    const float* norm1_b    = (const float*)d_in[2];
    const float* qkv_self_w = (const float*)d_in[3];
    const float* qkv_self_b = (const float*)d_in[4];
    const float* qkv_mut_w  = (const float*)d_in[5];
    const float* qkv_mut_b  = (const float*)d_in[6];
    const float* proj_w     = (const float*)d_in[7];
    const float* proj_b     = (const float*)d_in[8];
    const float* norm2_w    = (const float*)d_in[9];
    const float* norm2_b    = (const float*)d_in[10];
    const float* fc11_w     = (const float*)d_in[11];
    const float* fc11_b     = (const float*)d_in[12];
    const float* fc12_w     = (const float*)d_in[13];
    const float* fc12_b     = (const float*)d_in[14];
    const float* fc2_w      = (const float*)d_in[15];
    const float* fc2_b      = (const float*)d_in[16];

    if (ws_size < 110100480u) return;

    char* wsb   = (char*)d_ws;
    short* Hb    = (short*)wsb;                   // 131072x120 bf16
    short* QKVc  = (short*)(wsb + 31457280);      // 3 planes, chunk
    short* XOUTc = (short*)(wsb + 78643200);      // 65536x240 bf16
    float* TMPc  = (float*)(wsb + 31457280);      // 65536x120 fp32 (over dead QKV)
    short* H2c   = (short*)(wsb + 62914560);      // 65536x120 bf16 (over dead QKV)
    short* HIDc  = (short*)(wsb + 78643200);      // 65536x240 bf16 (over dead XOUT)
    float* out   = (float*)d_out;                 // final output only

    // 1. LN1 + window partition -> Hb (bf16)
    ln_kernel<true><<<16384, 256, 0, stream>>>(x, norm1_w, norm1_b, Hb);

    // 2. Per-chunk: attention + MLP (row-local after attn; no d_out scratch)
    for (int c = 0; c < 2; ++c) {
        int m0 = c * CHROWS;
        const short* Ac = Hb + (size_t)m0 * 120;
        mm<0, 120, 360, 4, 4><<<dim3(256, 6), 256, 0, stream>>>(Ac, qkv_self_w, qkv_self_b,
                                                                QKVc, nullptr, 0);
        attn_flash<256, false><<<1536, 256, 0, stream>>>(QKVc, XOUTc);
        mm<0, 120, 360, 4, 4><<<dim3(256, 6), 256, 0, stream>>>(Ac, qkv_mut_w, qkv_mut_b,
                                                                QKVc, nullptr, 0);
        attn_flash<128, true><<<3072, 128, 0, stream>>>(QKVc, XOUTc);
        mm<1, 240, 120, 4, 4><<<dim3(256, 2), 256, 0, stream>>>(XOUTc, proj_w, proj_b,
                                                                TMPc, x, m0);
        ln_kernel<false><<<8192, 256, 0, stream>>>(TMPc, norm2_w, norm2_b, H2c);
        mm_mlp<<<dim3(256, 4), 512, 0, stream>>>(H2c, fc11_w, fc11_b,
                                                 fc12_w, fc12_b, HIDc);
        mm<4, 240, 120, 4, 4><<<dim3(256, 2), 256, 0, stream>>>(HIDc, fc2_w, fc2_b,
                                                                out, TMPc, m0);
    }
}